// Round 9
// baseline (849.122 us; speedup 1.0000x reference)
//
#include <hip/hip_runtime.h>
#include <math.h>

#define NNODES 50000
#define NEDGES 800000
#define NGRAPH 512
#define FIN    256
#define H1     256
#define H2     256
#define H3     512
#define FPOUT  2048

#define NBUCK  196     // ceil(NNODES/256) coarse buckets (256 nodes each)
#define EPB    3200    // edges per binA block (250 blocks x 3200 = 800000 exactly)
#define BCAP   4864    // binB LDS chunk capacity (mean 4096, +12 sigma)

typedef __attribute__((ext_vector_type(8))) short short8;
typedef __attribute__((ext_vector_type(8))) _Float16 half8;
typedef __attribute__((ext_vector_type(4))) float floatx4;
typedef __attribute__((ext_vector_type(4))) unsigned short ushx4;

// fp16 helpers: v_cvt_f16_f32 is RNE on gfx950
__device__ inline float h2f(ushort u) { return (float)__builtin_bit_cast(_Float16, u); }
__device__ inline ushort f2h(float x) { return __builtin_bit_cast(ushort, (_Float16)x); }
// Dekker split: a = hi + lo with hi = RNE-fp16(a); lo carries ~11 more mantissa bits.
__device__ inline void split2h(float a, ushort& h, ushort& l) {
    _Float16 hh = (_Float16)a;
    h = __builtin_bit_cast(ushort, hh);
    l = f2h(a - (float)hh);
}

// ---------------- utility kernels ----------------

__global__ __launch_bounds__(256) void zero_i32(int* p, int n) {
    int i = blockIdx.x * 256 + threadIdx.x;
    if (i < n) p[i] = 0;
}

__global__ __launch_bounds__(256) void count_deg(const int* __restrict__ ei, int* __restrict__ degi, int e_total) {
    int e = blockIdx.x * 256 + threadIdx.x;
    if (e >= e_total) return;
    int d = ei[e_total + e];
    atomicAdd(&degi[d], 1);
}

__global__ __launch_bounds__(256) void calc_dis(const int* __restrict__ degi, float* __restrict__ dis, int n) {
    int i = blockIdx.x * 256 + threadIdx.x;
    if (i < n) dis[i] = rsqrtf((float)(degi[i] + 1));   // +1 self loop
}

__global__ __launch_bounds__(256) void scanA(const int* __restrict__ degi, int* __restrict__ offs,
                                             int* __restrict__ partials, int n) {
    __shared__ int sm[256];
    int t = threadIdx.x, idx = blockIdx.x * 256 + t;
    int v = (idx < n) ? degi[idx] : 0;
    sm[t] = v; __syncthreads();
    for (int d = 1; d < 256; d <<= 1) {
        int add = (t >= d) ? sm[t - d] : 0;
        __syncthreads();
        sm[t] += add;
        __syncthreads();
    }
    if (idx < n) offs[idx + 1] = sm[t];
    if (t == 255) partials[blockIdx.x] = sm[255];
}

__global__ __launch_bounds__(256) void scanB(int* __restrict__ partials, int nb) {
    __shared__ int sm[256];
    int t = threadIdx.x;
    int v = (t < nb) ? partials[t] : 0;
    sm[t] = v; __syncthreads();
    for (int d = 1; d < 256; d <<= 1) {
        int add = (t >= d) ? sm[t - d] : 0;
        __syncthreads();
        sm[t] += add;
        __syncthreads();
    }
    if (t < nb) partials[t] = sm[t] - v;   // exclusive
}

__global__ __launch_bounds__(256) void scanC(int* __restrict__ offs, const int* __restrict__ partials, int n) {
    int idx = blockIdx.x * 256 + threadIdx.x;
    if (idx < n) offs[idx + 1] += partials[blockIdx.x];
    if (idx == 0) offs[0] = 0;
}

// ---------------- CSR build via two-pass binning (R8, proven) ----------------
__global__ __launch_bounds__(256) void binA(const int* __restrict__ ei, const int* __restrict__ offs,
                                            int* __restrict__ gcur, int2* __restrict__ tmp, int e_total) {
    __shared__ int2 ls[EPB];
    __shared__ int2 ls2[EPB];
    __shared__ int hist[256], lpref[256], lcur[256], gbase[256], obase[256];
    int tid = threadIdx.x;
    int e0 = blockIdx.x * EPB;
    int cnt = e_total - e0; if (cnt > EPB) cnt = EPB;
    hist[tid] = 0;
    __syncthreads();
    for (int i = tid; i < cnt; i += 256) {
        int s = ei[e0 + i];
        int d = ei[e_total + e0 + i];
        ls[i] = (int2){s, d};
        atomicAdd(&hist[d >> 8], 1);
    }
    __syncthreads();
    int hv = hist[tid];
    lpref[tid] = hv;
    __syncthreads();
    for (int dlt = 1; dlt < 256; dlt <<= 1) {
        int add = (tid >= dlt) ? lpref[tid - dlt] : 0;
        __syncthreads();
        lpref[tid] += add;
        __syncthreads();
    }
    int excl = lpref[tid] - hv;
    __syncthreads();
    lpref[tid] = excl;
    lcur[tid] = 0;
    __syncthreads();
    for (int i = tid; i < cnt; i += 256) {
        int2 pr = ls[i];
        int b = pr.y >> 8;
        int r = atomicAdd(&lcur[b], 1);
        ls2[lpref[b] + r] = pr;
    }
    if (tid < NBUCK) {
        int c = hist[tid];
        gbase[tid] = c ? atomicAdd(&gcur[tid], c) : 0;
        obase[tid] = offs[tid << 8];
    }
    __syncthreads();
    for (int i = tid; i < cnt; i += 256) {
        int2 pr = ls2[i];
        int b = pr.y >> 8;
        tmp[obase[b] + gbase[b] + (i - lpref[b])] = pr;
    }
}

__global__ __launch_bounds__(256) void binB(const int2* __restrict__ tmp, const int* __restrict__ offs,
                                            const float* __restrict__ dis, int2* __restrict__ csr_pair) {
    __shared__ int2 ls[BCAP];
    __shared__ int cntN[256];
    int tid = threadIdx.x;
    int b = blockIdx.x;
    int nlo = b << 8;
    int nhi = nlo + 256; if (nhi > NNODES) nhi = NNODES;
    int base = offs[nlo];
    int tot = offs[nhi] - base;
    cntN[tid] = 0;
    __syncthreads();
    for (int c0 = 0; c0 < tot; c0 += BCAP) {
        int cc = tot - c0; if (cc > BCAP) cc = BCAP;
        for (int i = tid; i < cc; i += 256)
            ls[i] = tmp[base + c0 + i];
        __syncthreads();
        for (int i = tid; i < cc; i += 256) {
            int2 pr = ls[i];
            int d = pr.y;
            int r = atomicAdd(&cntN[d & 255], 1);
            float w = dis[pr.x] * dis[d];
            csr_pair[offs[d] + r] = (int2){pr.x, __float_as_int(w)};
        }
        __syncthreads();
    }
}

// ---------------- degree-sort permutation: aux[slot] = {v, beg, deg, dis_bits} ----------------
// Counting sort by degree (bin = min(deg,255)). Waves of 16 equal-degree nodes -> no
// wave-max waste in agg. Per-node summation order unchanged -> identical numerics.
__global__ __launch_bounds__(256) void deg_hist(const int* __restrict__ degi, int* __restrict__ hist, int n) {
    int i = blockIdx.x * 256 + threadIdx.x;
    if (i >= n) return;
    int d = degi[i];
    atomicAdd(&hist[d > 255 ? 255 : d], 1);
}

__global__ __launch_bounds__(256) void scan256(int* __restrict__ buf) {
    __shared__ int sm[256];
    int t = threadIdx.x;
    int v = buf[t];
    sm[t] = v; __syncthreads();
    for (int d = 1; d < 256; d <<= 1) {
        int add = (t >= d) ? sm[t - d] : 0;
        __syncthreads();
        sm[t] += add;
        __syncthreads();
    }
    buf[t] = sm[t] - v;   // exclusive
}

__global__ __launch_bounds__(256) void deg_scatter(const int* __restrict__ degi, const int* __restrict__ offs,
                                                   const float* __restrict__ dis, const int* __restrict__ hbase,
                                                   int* __restrict__ hcur, int4* __restrict__ aux, int n) {
    int i = blockIdx.x * 256 + threadIdx.x;
    if (i >= n) return;
    int d = degi[i];
    int b = d > 255 ? 255 : d;
    int r = atomicAdd(&hcur[b], 1);
    int4 e;
    e.x = i; e.y = offs[i]; e.z = d; e.w = __float_as_int(dis[i]);
    aux[hbase[b] + r] = e;
}

// W[K][N] fp32 -> Wt_hi[N][K], Wt_lo[N][K] (fp16 Dekker pair): LDS-tiled transpose
__global__ __launch_bounds__(256) void wsplit_t(const float* __restrict__ W, ushort* __restrict__ hi,
                                                ushort* __restrict__ lo, int K, int N) {
    __shared__ float sm[32][33];
    int tx = threadIdx.x & 31, ty = threadIdx.x >> 5;   // 32 x 8
    int n0 = blockIdx.x * 32, k0 = blockIdx.y * 32;
    #pragma unroll
    for (int j = 0; j < 32; j += 8)
        sm[ty + j][tx] = W[(size_t)(k0 + ty + j) * N + n0 + tx];
    __syncthreads();
    #pragma unroll
    for (int j = 0; j < 32; j += 8) {
        float a = sm[tx][ty + j];
        ushort h, l; split2h(a, h, l);
        size_t o = (size_t)(n0 + ty + j) * K + k0 + tx;
        hi[o] = h; lo[o] = l;
    }
}

// x fp32 -> fp16 table, CHUNK-MAJOR layout [8][NNODES][32] (refcheck'd in R5-R7):
// element (node n, feat f) -> xh[((f>>5)*NNODES + n)*32 + (f&31)]
__global__ __launch_bounds__(256) void conv_f16(const float* __restrict__ x, ushort* __restrict__ xh, int total4) {
    int i = blockIdx.x * 256 + threadIdx.x;
    if (i >= total4) return;
    int n  = i >> 6;          // node
    int f4 = i & 63;          // float-quad within row (f = f4*4)
    float4 a = ((const float4*)x)[i];
    ushx4 h = {f2h(a.x), f2h(a.y), f2h(a.z), f2h(a.w)};
    size_t o4 = (((size_t)(f4 >> 3) * NNODES + n) * 32 + (f4 & 7) * 4) >> 2;  // ushx4 index
    ((ushx4*)xh)[o4] = h;
}

// ---------------- MFMA fp16 GEMM: BK=64, XOR-swizzled LDS, XCD-chunked blocks ----------------
// SPLIT=0: C = relu(A @ B^T + bias), single fp16 operands, 1 MFMA per frag pair.
// SPLIT=1: fp16 Dekker pairs, 3 MFMAs (~fp32-accurate). Head GEMM.
// ACC=1: raw acc to partial buffer C + z*M*N (split-K).
// outmode 1: write fp16 activation table CHUNK-MAJOR [N/32][M][32].
template<int SPLIT, int ACC, int KSPAN>
__global__ __launch_bounds__(256) void gemm_f16(const ushort* __restrict__ Ahp, const ushort* __restrict__ Alp,
                                                const ushort* __restrict__ Bhp, const ushort* __restrict__ Blp,
                                                float* __restrict__ C, ushort* __restrict__ Ch,
                                                const float* __restrict__ bias,
                                                int M, int N, int K, int do_relu, int outmode) {
    __shared__ _Float16 lsA[128 * 64];
    __shared__ _Float16 lsB[128 * 64];
    __shared__ _Float16 lsAl[SPLIT ? 128 * 64 : 8];
    __shared__ _Float16 lsBl[SPLIT ? 128 * 64 : 8];
    const _Float16* Ah = (const _Float16*)Ahp;
    const _Float16* Al = (const _Float16*)Alp;
    const _Float16* Bh = (const _Float16*)Bhp;
    const _Float16* Bl = (const _Float16*)Blp;

    int tid = threadIdx.x;
    int w = tid >> 6, lane = tid & 63;
    int quad = lane >> 4, lr = lane & 15;
    int wm = w & 1, wn = w >> 1;

    int gx = gridDim.x;
    int orig = blockIdx.y * gx + blockIdx.x;
    int nwg = gx * gridDim.y;
    int xcd = orig & 7, slot = orig >> 3;
    int q = nwg >> 3, r = nwg & 7;
    int wid = (xcd < r ? xcd * (q + 1) : r * (q + 1) + (xcd - r) * q) + slot;
    int row0 = (wid / gx) * 128, col0 = (wid % gx) * 128;
    int kb = blockIdx.z * KSPAN;

    floatx4 acc[4][4];
    #pragma unroll
    for (int i = 0; i < 4; ++i)
        #pragma unroll
        for (int j = 0; j < 4; ++j)
            acc[i][j] = (floatx4){0.f, 0.f, 0.f, 0.f};

    const half8 zer = {};
    int srow = tid >> 3;
    int sgran = tid & 7;
    int skk = sgran * 8;
    int sgx = (sgran ^ (srow & 7)) * 8;

    half8 pa[4], pb[4], pal[4], pbl[4];
    #pragma unroll
    for (int c = 0; c < 4; ++c) {
        int row = c * 32 + srow;
        bool mok = (row0 + row) < M;
        size_t aoff = (size_t)(row0 + row) * K + kb + skk;
        pa[c] = mok ? *(const half8*)(Ah + aoff) : zer;
        if constexpr (SPLIT) pal[c] = mok ? *(const half8*)(Al + aoff) : zer;
        size_t boff = (size_t)(col0 + row) * K + kb + skk;
        pb[c] = *(const half8*)(Bh + boff);
        if constexpr (SPLIT) pbl[c] = *(const half8*)(Bl + boff);
    }

    for (int k0 = kb; k0 < kb + KSPAN; k0 += 64) {
        #pragma unroll
        for (int c = 0; c < 4; ++c) {
            int lo = (c * 32 + srow) * 64 + sgx;
            *(half8*)(lsA + lo) = pa[c];
            *(half8*)(lsB + lo) = pb[c];
            if constexpr (SPLIT) { *(half8*)(lsAl + lo) = pal[c]; *(half8*)(lsBl + lo) = pbl[c]; }
        }
        __syncthreads();
        if (k0 + 64 < kb + KSPAN) {
            #pragma unroll
            for (int c = 0; c < 4; ++c) {
                int row = c * 32 + srow;
                bool mok = (row0 + row) < M;
                size_t aoff = (size_t)(row0 + row) * K + k0 + 64 + skk;
                pa[c] = mok ? *(const half8*)(Ah + aoff) : zer;
                if constexpr (SPLIT) pal[c] = mok ? *(const half8*)(Al + aoff) : zer;
                size_t boff = (size_t)(col0 + row) * K + k0 + 64 + skk;
                pb[c] = *(const half8*)(Bh + boff);
                if constexpr (SPLIT) pbl[c] = *(const half8*)(Bl + boff);
            }
        }
        #pragma unroll
        for (int kk = 0; kk < 2; ++kk) {
            half8 af[4], afl[4];
            #pragma unroll
            for (int mt = 0; mt < 4; ++mt) {
                int row = wm * 64 + mt * 16 + lr;
                int ao = row * 64 + (((kk * 4 + quad) ^ (row & 7)) << 3);
                af[mt] = *(const half8*)(lsA + ao);
                if constexpr (SPLIT) afl[mt] = *(const half8*)(lsAl + ao);
            }
            #pragma unroll
            for (int nt = 0; nt < 4; ++nt) {
                int row = wn * 64 + nt * 16 + lr;
                int bo = row * 64 + (((kk * 4 + quad) ^ (row & 7)) << 3);
                half8 bf = *(const half8*)(lsB + bo);
                half8 bfl;
                if constexpr (SPLIT) bfl = *(const half8*)(lsBl + bo);
                #pragma unroll
                for (int mt = 0; mt < 4; ++mt) {
                    acc[mt][nt] = __builtin_amdgcn_mfma_f32_16x16x32_f16(af[mt], bf, acc[mt][nt], 0, 0, 0);
                    if constexpr (SPLIT) {
                        acc[mt][nt] = __builtin_amdgcn_mfma_f32_16x16x32_f16(af[mt], bfl, acc[mt][nt], 0, 0, 0);
                        acc[mt][nt] = __builtin_amdgcn_mfma_f32_16x16x32_f16(afl[mt], bf, acc[mt][nt], 0, 0, 0);
                    }
                }
            }
        }
        __syncthreads();
    }

    size_t zoff = ACC ? (size_t)blockIdx.z * M * N : 0;
    #pragma unroll
    for (int mt = 0; mt < 4; ++mt) {
        #pragma unroll
        for (int rr = 0; rr < 4; ++rr) {
            int row = row0 + wm * 64 + mt * 16 + quad * 4 + rr;
            if (row >= M) continue;
            #pragma unroll
            for (int nt = 0; nt < 4; ++nt) {
                int col = col0 + wn * 64 + nt * 16 + lr;
                float v = acc[mt][nt][rr];
                if (!ACC) {
                    v += bias[col];
                    if (do_relu) v = v > 0.f ? v : 0.f;
                }
                if (outmode) Ch[((size_t)(col >> 5) * M + row) * 32 + (col & 31)] = f2h(v);
                else         C[zoff + (size_t)row * N + col] = v;
            }
        }
    }
}

// finish for split-K head: out = relu(sum_z partials + bias), vectorized float4
__global__ __launch_bounds__(256) void head_fin(const float* __restrict__ part, const float* __restrict__ bo,
                                                float* __restrict__ out) {
    int i4 = blockIdx.x * 256 + threadIdx.x;
    const int TOT4 = NGRAPH * FPOUT / 4;
    if (i4 >= TOT4) return;
    int col4 = i4 & (FPOUT / 4 - 1);
    const size_t STRIDE4 = (size_t)NGRAPH * FPOUT / 4;
    const float4* p = (const float4*)part;
    float4 a = p[i4];
    float4 b = p[i4 + STRIDE4];
    float4 c = p[i4 + 2 * STRIDE4];
    float4 d = p[i4 + 3 * STRIDE4];
    float4 bb = ((const float4*)bo)[col4];
    float4 o;
    o.x = a.x + b.x + c.x + d.x + bb.x; o.x = o.x > 0.f ? o.x : 0.f;
    o.y = a.y + b.y + c.y + d.y + bb.y; o.y = o.y > 0.f ? o.y : 0.f;
    o.z = a.z + b.z + c.z + d.z + bb.z; o.z = o.z > 0.f ? o.z : 0.f;
    o.w = a.w + b.w + c.w + d.w + bb.w; o.w = o.w > 0.f ? o.w : 0.f;
    ((float4*)out)[i4] = o;
}

// ---------------- aggregation: chunk-affine, 16 nodes/block, edge-split waves ----------------
// chunk = blk&7 -> XCD-pinned 3.2MB slice (R5-proven, FETCH 58MB). 16 nodes/block keeps the
// concurrent csr window ~0.56MB (R7's 2.2MB overflowed). 4 waves split each node's edges
// mod 4 (full-occupancy latency hiding, dense issue); partial sums via padded LDS.
// aux = degree-sorted {v,beg,deg,dis}: equal-degree waves -> no wave-max waste; streamed
// 16B reads replace random offs/dis. Per-node summation order unchanged (csr order).
__global__ __launch_bounds__(256) void agg_chunk(const ushort* __restrict__ xh, ushort* __restrict__ yh,
                                                 const int4* __restrict__ aux,
                                                 const int2* __restrict__ csr_pair) {
    __shared__ float sm[4][64][9];   // +1 pad: conflict-free lane-major access
    int wave = threadIdx.x >> 6;
    int lane = threadIdx.x & 63;
    int nd = lane >> 2, quad = lane & 3;
    int chunk = blockIdx.x & 7;                      // XCD-affine
    int slot = (blockIdx.x >> 3) * 16 + nd;          // 50000 = 16*3125 exactly
    int4 a = aux[slot];
    int v = a.x, beg = a.y, deg = a.z;
    float dv = __int_as_float(a.w);
    float sw = dv * dv;
    const _Float16* xc = (const _Float16*)xh + (size_t)chunk * NNODES * 32;

    float acc[8];
    if (wave == 0) {
        half8 g0 = *(const half8*)(xc + (size_t)v * 32 + quad * 8);
        #pragma unroll
        for (int j = 0; j < 8; ++j) acc[j] = (float)g0[j] * sw;   // self-loop
    } else {
        #pragma unroll
        for (int j = 0; j < 8; ++j) acc[j] = 0.f;
    }

    int md = deg;
    #pragma unroll
    for (int m = 4; m <= 32; m <<= 1) { int o = __shfl_xor(md, m, 64); md = md > o ? md : o; }

    for (int k8 = 0; k8 < md; k8 += 8) {
        int s[2]; float w[2];
        #pragma unroll
        for (int u = 0; u < 2; ++u) {
            int e = k8 + u * 4 + wave;               // wave covers e == wave (mod 4)
            bool val = e < deg;
            int2 pr = csr_pair[val ? (beg + e) : beg];
            s[u] = val ? pr.x : 0;
            w[u] = val ? __int_as_float(pr.y) : 0.f;
        }
        half8 g[2];
        #pragma unroll
        for (int u = 0; u < 2; ++u)
            g[u] = *(const half8*)(xc + (size_t)s[u] * 32 + quad * 8);
        #pragma unroll
        for (int u = 0; u < 2; ++u)
            #pragma unroll
            for (int j = 0; j < 8; ++j) acc[j] += (float)g[u][j] * w[u];
    }

    #pragma unroll
    for (int j = 0; j < 8; ++j) sm[wave][lane][j] = acc[j];
    __syncthreads();
    if (wave == 0) {
        #pragma unroll
        for (int wv = 1; wv < 4; ++wv)
            #pragma unroll
            for (int j = 0; j < 8; ++j) acc[j] += sm[wv][lane][j];
        ushort h[8];
        #pragma unroll
        for (int j = 0; j < 8; ++j) h[j] = f2h(acc[j]);
        short8 hv = {(short)h[0], (short)h[1], (short)h[2], (short)h[3],
                     (short)h[4], (short)h[5], (short)h[6], (short)h[7]};
        *(short8*)(yh + (size_t)v * 256 + chunk * 32 + quad * 8) = hv;
    }
}

// ---------------- fused gate+pool: per graph, 16 waves ----------------
__global__ __launch_bounds__(1024) void gatepool(const float* __restrict__ x, const float* __restrict__ pw,
                                                 const float* __restrict__ pb, const int* __restrict__ batch,
                                                 ushort* __restrict__ phi, ushort* __restrict__ plo, int n) {
    int g = blockIdx.x;
    int t = threadIdx.x;
    int wave = t >> 6, lane = t & 63;
    int lo_ = 0, hi_ = n;
    while (lo_ < hi_) { int mid = (lo_ + hi_) >> 1; if (batch[mid] < g) lo_ = mid + 1; else hi_ = mid; }
    int start = lo_;
    hi_ = n;
    while (lo_ < hi_) { int mid = (lo_ + hi_) >> 1; if (batch[mid] < g + 1) lo_ = mid + 1; else hi_ = mid; }
    int end = lo_;

    const float4* pwv = (const float4*)pw;
    float4 wa = pwv[lane], wb = pwv[lane + 64];
    float pb0 = pb[0];

    float4 s0 = make_float4(0.f, 0.f, 0.f, 0.f), s1 = s0;
    float4 m0 = make_float4(-INFINITY, -INFINITY, -INFINITY, -INFINITY), m1 = m0;

    for (int nn = start + wave; nn < end; nn += 16) {
        const float4* xr = (const float4*)(x + (size_t)nn * 512);
        float4 a = xr[lane];
        float4 b = xr[lane + 64];
        float p = a.x * wa.x + a.y * wa.y + a.z * wa.z + a.w * wa.w
                + b.x * wb.x + b.y * wb.y + b.z * wb.z + b.w * wb.w;
        #pragma unroll
        for (int off = 32; off; off >>= 1) p += __shfl_down(p, off, 64);
        float wg = __shfl(p, 0, 64);
        wg = 1.f / (1.f + expf(-(wg + pb0)));
        s0.x += a.x * wg; s0.y += a.y * wg; s0.z += a.z * wg; s0.w += a.w * wg;
        s1.x += b.x * wg; s1.y += b.y * wg; s1.z += b.z * wg; s1.w += b.w * wg;
        m0.x = fmaxf(m0.x, a.x); m0.y = fmaxf(m0.y, a.y); m0.z = fmaxf(m0.z, a.z); m0.w = fmaxf(m0.w, a.w);
        m1.x = fmaxf(m1.x, b.x); m1.y = fmaxf(m1.y, b.y); m1.z = fmaxf(m1.z, b.z); m1.w = fmaxf(m1.w, b.w);
    }

    __shared__ float ls[16][1024];
    *(float4*)&ls[wave][lane * 4]       = s0;
    *(float4*)&ls[wave][256 + lane * 4] = s1;
    *(float4*)&ls[wave][512 + lane * 4] = m0;
    *(float4*)&ls[wave][768 + lane * 4] = m1;
    __syncthreads();

    float val;
    if (t < 512) {
        float s = 0.f;
        #pragma unroll
        for (int wv = 0; wv < 16; ++wv) s += ls[wv][t];
        val = s;
    } else {
        float m = -INFINITY;
        #pragma unroll
        for (int wv = 0; wv < 16; ++wv) m = fmaxf(m, ls[wv][t]);
        if (start >= end) m = 0.f;
        val = m;
    }
    ushort h, l;
    split2h(val, h, l);
    size_t base = (size_t)g * 1024;
    phi[base + t] = h;
    plo[base + t] = l;
}

// ---------------- launch ----------------

extern "C" void kernel_launch(void* const* d_in, const int* in_sizes, int n_in,
                              void* d_out, int out_size, void* d_ws, size_t ws_size,
                              hipStream_t stream) {
    const float* x0    = (const float*)d_in[0];
    const int*   ei    = (const int*)d_in[1];
    const int*   batch = (const int*)d_in[2];
    const float* W1 = (const float*)d_in[3];
    const float* b1 = (const float*)d_in[4];
    const float* W2 = (const float*)d_in[5];
    const float* b2 = (const float*)d_in[6];
    const float* W3 = (const float*)d_in[7];
    const float* b3 = (const float*)d_in[8];
    const float* pw = (const float*)d_in[9];
    const float* pb = (const float*)d_in[10];
    const float* Wo = (const float*)d_in[11];
    const float* bo = (const float*)d_in[12];
    float* out = (float*)d_out;

    // workspace layout (float units, 16B-aligned regions)
    float* ws = (float*)d_ws;
    size_t off = 0;
    float* bufB = ws + off; off += (size_t)NNODES * 512;                 // x3 fp32 / head split-K partials
    ushort* xh  = (ushort*)(ws + off); off += (size_t)NNODES * 256 / 2;  // activation fp16 table (chunk-major)
    ushort* yh  = (ushort*)(ws + off); off += (size_t)NNODES * 256 / 2;  // agg out fp16 (row-major)
    int2*   tmp = (int2*)(ws + off);   off += (size_t)NNODES * 256 / 2;  // binA {s,d} intermediate
    ushort* W1thi = (ushort*)(ws + off); off += 256 * 256 / 2;
    ushort* W1tlo = (ushort*)(ws + off); off += 256 * 256 / 2;
    ushort* W2thi = (ushort*)(ws + off); off += 256 * 256 / 2;
    ushort* W2tlo = (ushort*)(ws + off); off += 256 * 256 / 2;
    ushort* W3thi = (ushort*)(ws + off); off += 512 * 256 / 2;
    ushort* W3tlo = (ushort*)(ws + off); off += 512 * 256 / 2;
    ushort* Wothi = (ushort*)(ws + off); off += (size_t)FPOUT * 1024 / 2;
    ushort* Wotlo = (ushort*)(ws + off); off += (size_t)FPOUT * 1024 / 2;
    ushort* phi = (ushort*)(ws + off); off += (size_t)NGRAPH * 1024 / 2;
    ushort* plo = (ushort*)(ws + off); off += (size_t)NGRAPH * 1024 / 2;
    float* dis  = ws + off; off += NNODES;
    int*   degi = (int*)(ws + off); off += NNODES;
    int*   offs = (int*)(ws + off); off += (NNODES + 4);
    int*   gcur = (int*)(ws + off); off += 256;                          // binA bucket cursors
    int2*  csr_pair = (int2*)(ws + off); off += 2 * (size_t)NEDGES;      // packed {src, w}
    int*   partials = (int*)(ws + off); off += 256;
    int*   hist = (int*)(ws + off); off += 256;                          // degree histogram -> bases
    int*   hcur = (int*)(ws + off); off += 256;                          // degree scatter cursors
    int4*  aux  = (int4*)(ws + off); off += (size_t)NNODES * 4;          // sorted {v,beg,deg,dis}

    const int NB_N = (NNODES + 255) / 256;   // 196
    const int NB_E = (NEDGES + 255) / 256;
    const int NB_A = (NNODES / 16) * 8;      // 3125 node groups x 8 chunks = 25000 blocks
    const int MB128 = (NNODES + 127) / 128;  // 391

    // weight transpose+split (LDS-tiled, coalesced); layers use hi (= RNE fp16 W) only
    { dim3 g(256 / 32, 256 / 32);    wsplit_t<<<g, 256, 0, stream>>>(W1, W1thi, W1tlo, 256, 256); }
    { dim3 g(256 / 32, 256 / 32);    wsplit_t<<<g, 256, 0, stream>>>(W2, W2thi, W2tlo, 256, 256); }
    { dim3 g(512 / 32, 256 / 32);    wsplit_t<<<g, 256, 0, stream>>>(W3, W3thi, W3tlo, 256, 512); }
    { dim3 g(FPOUT / 32, 1024 / 32); wsplit_t<<<g, 256, 0, stream>>>(Wo, Wothi, Wotlo, 1024, FPOUT); }

    // CSR build: degree count -> offsets -> two-pass binning
    zero_i32<<<NB_N, 256, 0, stream>>>(degi, NNODES);
    count_deg<<<NB_E, 256, 0, stream>>>(ei, degi, NEDGES);
    calc_dis<<<NB_N, 256, 0, stream>>>(degi, dis, NNODES);
    scanA<<<NB_N, 256, 0, stream>>>(degi, offs, partials, NNODES);
    scanB<<<1, 256, 0, stream>>>(partials, NB_N);
    scanC<<<NB_N, 256, 0, stream>>>(offs, partials, NNODES);
    zero_i32<<<1, 256, 0, stream>>>(gcur, 256);
    binA<<<NEDGES / EPB, 256, 0, stream>>>(ei, offs, gcur, tmp, NEDGES);
    binB<<<NBUCK, 256, 0, stream>>>(tmp, offs, dis, csr_pair);

    // degree-sort permutation -> aux
    zero_i32<<<1, 256, 0, stream>>>(hist, 256);
    deg_hist<<<NB_N, 256, 0, stream>>>(degi, hist, NNODES);
    scan256<<<1, 256, 0, stream>>>(hist);
    zero_i32<<<1, 256, 0, stream>>>(hcur, 256);
    deg_scatter<<<NB_N, 256, 0, stream>>>(degi, offs, dis, hist, hcur, aux, NNODES);

    // x0 -> fp16 table (chunk-major)
    conv_f16<<<(NNODES * 256 / 4 + 255) / 256, 256, 0, stream>>>(x0, xh, NNODES * 256 / 4);

    // layer 1: y = A_norm @ x0h ; x1h = fp16(relu(y @ W1 + b1)) (chunk-major)
    agg_chunk<<<NB_A, 256, 0, stream>>>(xh, yh, aux, csr_pair);
    {
        dim3 grid(H1 / 128, MB128);
        gemm_f16<0, 0, 256><<<grid, 256, 0, stream>>>(yh, nullptr, W1thi, nullptr, nullptr, xh, b1,
                                                      NNODES, H1, FIN, 1, 1);
    }
    // layer 2
    agg_chunk<<<NB_A, 256, 0, stream>>>(xh, yh, aux, csr_pair);
    {
        dim3 grid(H2 / 128, MB128);
        gemm_f16<0, 0, 256><<<grid, 256, 0, stream>>>(yh, nullptr, W2thi, nullptr, nullptr, xh, b2,
                                                      NNODES, H2, H1, 1, 1);
    }
    // layer 3: agg on x2h, GEMM 256->512 -> fp32 (gatepool input)
    agg_chunk<<<NB_A, 256, 0, stream>>>(xh, yh, aux, csr_pair);
    {
        dim3 grid(H3 / 128, MB128);
        gemm_f16<0, 0, 256><<<grid, 256, 0, stream>>>(yh, nullptr, W3thi, nullptr, bufB, nullptr, b3,
                                                      NNODES, H3, H2, 1, 0);
    }
    // fused gate+pool -> pooled fp16 hi/lo (Dekker pairs)
    gatepool<<<NGRAPH, 1024, 0, stream>>>(bufB, pw, pb, batch, phi, plo, NNODES);
    // head: split-K over 4 z-slices into bufB partials, then bias+relu finish.
    {
        dim3 grid(FPOUT / 128, (NGRAPH + 127) / 128, 4);
        gemm_f16<1, 1, 256><<<grid, 256, 0, stream>>>(phi, plo, Wothi, Wotlo, bufB, nullptr, nullptr,
                                                      NGRAPH, FPOUT, 1024, 0, 0);
    }
    head_fin<<<(NGRAPH * FPOUT / 4 + 255) / 256, 256, 0, stream>>>(bufB, bo, out);
}

// Round 10
// 600.657 us; speedup vs baseline: 1.4137x; 1.4137x over previous
//
#include <hip/hip_runtime.h>
#include <math.h>

#define NNODES 50000
#define NEDGES 800000
#define NGRAPH 512
#define FIN    256
#define H1     256
#define H2     256
#define H3     512
#define FPOUT  2048

#define NBUCK  196     // ceil(NNODES/256) coarse buckets (256 nodes each)
#define EPB    3200    // edges per binA block (250 blocks x 3200 = 800000 exactly)
#define BCAP   4864    // binB LDS chunk capacity (mean 4096, +12 sigma)

typedef __attribute__((ext_vector_type(8))) short short8;
typedef __attribute__((ext_vector_type(8))) _Float16 half8;
typedef __attribute__((ext_vector_type(4))) float floatx4;
typedef __attribute__((ext_vector_type(4))) unsigned short ushx4;

// fp16 helpers: v_cvt_f16_f32 is RNE on gfx950
__device__ inline float h2f(ushort u) { return (float)__builtin_bit_cast(_Float16, u); }
__device__ inline ushort f2h(float x) { return __builtin_bit_cast(ushort, (_Float16)x); }
// Dekker split: a = hi + lo with hi = RNE-fp16(a); lo carries ~11 more mantissa bits.
__device__ inline void split2h(float a, ushort& h, ushort& l) {
    _Float16 hh = (_Float16)a;
    h = __builtin_bit_cast(ushort, hh);
    l = f2h(a - (float)hh);
}

// ---------------- utility kernels ----------------

__global__ __launch_bounds__(256) void zero_i32(int* p, int n) {
    int i = blockIdx.x * 256 + threadIdx.x;
    if (i < n) p[i] = 0;
}

__global__ __launch_bounds__(256) void count_deg(const int* __restrict__ ei, int* __restrict__ degi, int e_total) {
    int e = blockIdx.x * 256 + threadIdx.x;
    if (e >= e_total) return;
    int d = ei[e_total + e];
    atomicAdd(&degi[d], 1);
}

__global__ __launch_bounds__(256) void calc_dis(const int* __restrict__ degi, float* __restrict__ dis, int n) {
    int i = blockIdx.x * 256 + threadIdx.x;
    if (i < n) dis[i] = rsqrtf((float)(degi[i] + 1));   // +1 self loop
}

__global__ __launch_bounds__(256) void scanA(const int* __restrict__ degi, int* __restrict__ offs,
                                             int* __restrict__ partials, int n) {
    __shared__ int sm[256];
    int t = threadIdx.x, idx = blockIdx.x * 256 + t;
    int v = (idx < n) ? degi[idx] : 0;
    sm[t] = v; __syncthreads();
    for (int d = 1; d < 256; d <<= 1) {
        int add = (t >= d) ? sm[t - d] : 0;
        __syncthreads();
        sm[t] += add;
        __syncthreads();
    }
    if (idx < n) offs[idx + 1] = sm[t];
    if (t == 255) partials[blockIdx.x] = sm[255];
}

__global__ __launch_bounds__(256) void scanB(int* __restrict__ partials, int nb) {
    __shared__ int sm[256];
    int t = threadIdx.x;
    int v = (t < nb) ? partials[t] : 0;
    sm[t] = v; __syncthreads();
    for (int d = 1; d < 256; d <<= 1) {
        int add = (t >= d) ? sm[t - d] : 0;
        __syncthreads();
        sm[t] += add;
        __syncthreads();
    }
    if (t < nb) partials[t] = sm[t] - v;   // exclusive
}

__global__ __launch_bounds__(256) void scanC(int* __restrict__ offs, const int* __restrict__ partials, int n) {
    int idx = blockIdx.x * 256 + threadIdx.x;
    if (idx < n) offs[idx + 1] += partials[blockIdx.x];
    if (idx == 0) offs[0] = 0;
}

// ---------------- CSR build via two-pass binning (R8, proven) ----------------
__global__ __launch_bounds__(256) void binA(const int* __restrict__ ei, const int* __restrict__ offs,
                                            int* __restrict__ gcur, int2* __restrict__ tmp, int e_total) {
    __shared__ int2 ls[EPB];
    __shared__ int2 ls2[EPB];
    __shared__ int hist[256], lpref[256], lcur[256], gbase[256], obase[256];
    int tid = threadIdx.x;
    int e0 = blockIdx.x * EPB;
    int cnt = e_total - e0; if (cnt > EPB) cnt = EPB;
    hist[tid] = 0;
    __syncthreads();
    for (int i = tid; i < cnt; i += 256) {
        int s = ei[e0 + i];
        int d = ei[e_total + e0 + i];
        ls[i] = (int2){s, d};
        atomicAdd(&hist[d >> 8], 1);
    }
    __syncthreads();
    int hv = hist[tid];
    lpref[tid] = hv;
    __syncthreads();
    for (int dlt = 1; dlt < 256; dlt <<= 1) {
        int add = (tid >= dlt) ? lpref[tid - dlt] : 0;
        __syncthreads();
        lpref[tid] += add;
        __syncthreads();
    }
    int excl = lpref[tid] - hv;
    __syncthreads();
    lpref[tid] = excl;
    lcur[tid] = 0;
    __syncthreads();
    for (int i = tid; i < cnt; i += 256) {
        int2 pr = ls[i];
        int b = pr.y >> 8;
        int r = atomicAdd(&lcur[b], 1);
        ls2[lpref[b] + r] = pr;
    }
    if (tid < NBUCK) {
        int c = hist[tid];
        gbase[tid] = c ? atomicAdd(&gcur[tid], c) : 0;
        obase[tid] = offs[tid << 8];
    }
    __syncthreads();
    for (int i = tid; i < cnt; i += 256) {
        int2 pr = ls2[i];
        int b = pr.y >> 8;
        tmp[obase[b] + gbase[b] + (i - lpref[b])] = pr;
    }
}

__global__ __launch_bounds__(256) void binB(const int2* __restrict__ tmp, const int* __restrict__ offs,
                                            const float* __restrict__ dis, int2* __restrict__ csr_pair) {
    __shared__ int2 ls[BCAP];
    __shared__ int cntN[256];
    int tid = threadIdx.x;
    int b = blockIdx.x;
    int nlo = b << 8;
    int nhi = nlo + 256; if (nhi > NNODES) nhi = NNODES;
    int base = offs[nlo];
    int tot = offs[nhi] - base;
    cntN[tid] = 0;
    __syncthreads();
    for (int c0 = 0; c0 < tot; c0 += BCAP) {
        int cc = tot - c0; if (cc > BCAP) cc = BCAP;
        for (int i = tid; i < cc; i += 256)
            ls[i] = tmp[base + c0 + i];
        __syncthreads();
        for (int i = tid; i < cc; i += 256) {
            int2 pr = ls[i];
            int d = pr.y;
            int r = atomicAdd(&cntN[d & 255], 1);
            float w = dis[pr.x] * dis[d];
            csr_pair[offs[d] + r] = (int2){pr.x, __float_as_int(w)};
        }
        __syncthreads();
    }
}

// W[K][N] fp32 -> Wt_hi[N][K], Wt_lo[N][K] (fp16 Dekker pair): LDS-tiled transpose
__global__ __launch_bounds__(256) void wsplit_t(const float* __restrict__ W, ushort* __restrict__ hi,
                                                ushort* __restrict__ lo, int K, int N) {
    __shared__ float sm[32][33];
    int tx = threadIdx.x & 31, ty = threadIdx.x >> 5;   // 32 x 8
    int n0 = blockIdx.x * 32, k0 = blockIdx.y * 32;
    #pragma unroll
    for (int j = 0; j < 32; j += 8)
        sm[ty + j][tx] = W[(size_t)(k0 + ty + j) * N + n0 + tx];
    __syncthreads();
    #pragma unroll
    for (int j = 0; j < 32; j += 8) {
        float a = sm[tx][ty + j];
        ushort h, l; split2h(a, h, l);
        size_t o = (size_t)(n0 + ty + j) * K + k0 + tx;
        hi[o] = h; lo[o] = l;
    }
}

// x fp32 -> fp16-RNE table (row-major [NNODES][256])
__global__ __launch_bounds__(256) void conv_f16(const float* __restrict__ x, ushort* __restrict__ xh, int total4) {
    int i = blockIdx.x * 256 + threadIdx.x;
    if (i >= total4) return;
    float4 a = ((const float4*)x)[i];
    ushx4 h = {f2h(a.x), f2h(a.y), f2h(a.z), f2h(a.w)};
    ((ushx4*)xh)[i] = h;
}

// ---------------- MFMA fp16 GEMM: BK=64, XOR-swizzled LDS, XCD-chunked blocks ----------------
// SPLIT=0: C = relu(A @ B^T + bias), single fp16 operands, 1 MFMA per frag pair.
// SPLIT=1: fp16 Dekker pairs, 3 MFMAs (~fp32-accurate). Head GEMM.
// ACC=1: raw acc to partial buffer C + z*M*N (split-K).
// outmode 1: write fp16 activation table row-major [M][N].
template<int SPLIT, int ACC, int KSPAN>
__global__ __launch_bounds__(256) void gemm_f16(const ushort* __restrict__ Ahp, const ushort* __restrict__ Alp,
                                                const ushort* __restrict__ Bhp, const ushort* __restrict__ Blp,
                                                float* __restrict__ C, ushort* __restrict__ Ch,
                                                const float* __restrict__ bias,
                                                int M, int N, int K, int do_relu, int outmode) {
    __shared__ _Float16 lsA[128 * 64];
    __shared__ _Float16 lsB[128 * 64];
    __shared__ _Float16 lsAl[SPLIT ? 128 * 64 : 8];
    __shared__ _Float16 lsBl[SPLIT ? 128 * 64 : 8];
    const _Float16* Ah = (const _Float16*)Ahp;
    const _Float16* Al = (const _Float16*)Alp;
    const _Float16* Bh = (const _Float16*)Bhp;
    const _Float16* Bl = (const _Float16*)Blp;

    int tid = threadIdx.x;
    int w = tid >> 6, lane = tid & 63;
    int quad = lane >> 4, lr = lane & 15;
    int wm = w & 1, wn = w >> 1;

    int gx = gridDim.x;
    int orig = blockIdx.y * gx + blockIdx.x;
    int nwg = gx * gridDim.y;
    int xcd = orig & 7, slot = orig >> 3;
    int q = nwg >> 3, r = nwg & 7;
    int wid = (xcd < r ? xcd * (q + 1) : r * (q + 1) + (xcd - r) * q) + slot;
    int row0 = (wid / gx) * 128, col0 = (wid % gx) * 128;
    int kb = blockIdx.z * KSPAN;

    floatx4 acc[4][4];
    #pragma unroll
    for (int i = 0; i < 4; ++i)
        #pragma unroll
        for (int j = 0; j < 4; ++j)
            acc[i][j] = (floatx4){0.f, 0.f, 0.f, 0.f};

    const half8 zer = {};
    int srow = tid >> 3;
    int sgran = tid & 7;
    int skk = sgran * 8;
    int sgx = (sgran ^ (srow & 7)) * 8;

    half8 pa[4], pb[4], pal[4], pbl[4];
    #pragma unroll
    for (int c = 0; c < 4; ++c) {
        int row = c * 32 + srow;
        bool mok = (row0 + row) < M;
        size_t aoff = (size_t)(row0 + row) * K + kb + skk;
        pa[c] = mok ? *(const half8*)(Ah + aoff) : zer;
        if constexpr (SPLIT) pal[c] = mok ? *(const half8*)(Al + aoff) : zer;
        size_t boff = (size_t)(col0 + row) * K + kb + skk;
        pb[c] = *(const half8*)(Bh + boff);
        if constexpr (SPLIT) pbl[c] = *(const half8*)(Bl + boff);
    }

    for (int k0 = kb; k0 < kb + KSPAN; k0 += 64) {
        #pragma unroll
        for (int c = 0; c < 4; ++c) {
            int lo = (c * 32 + srow) * 64 + sgx;
            *(half8*)(lsA + lo) = pa[c];
            *(half8*)(lsB + lo) = pb[c];
            if constexpr (SPLIT) { *(half8*)(lsAl + lo) = pal[c]; *(half8*)(lsBl + lo) = pbl[c]; }
        }
        __syncthreads();
        if (k0 + 64 < kb + KSPAN) {
            #pragma unroll
            for (int c = 0; c < 4; ++c) {
                int row = c * 32 + srow;
                bool mok = (row0 + row) < M;
                size_t aoff = (size_t)(row0 + row) * K + k0 + 64 + skk;
                pa[c] = mok ? *(const half8*)(Ah + aoff) : zer;
                if constexpr (SPLIT) pal[c] = mok ? *(const half8*)(Al + aoff) : zer;
                size_t boff = (size_t)(col0 + row) * K + k0 + 64 + skk;
                pb[c] = *(const half8*)(Bh + boff);
                if constexpr (SPLIT) pbl[c] = *(const half8*)(Bl + boff);
            }
        }
        #pragma unroll
        for (int kk = 0; kk < 2; ++kk) {
            half8 af[4], afl[4];
            #pragma unroll
            for (int mt = 0; mt < 4; ++mt) {
                int row = wm * 64 + mt * 16 + lr;
                int ao = row * 64 + (((kk * 4 + quad) ^ (row & 7)) << 3);
                af[mt] = *(const half8*)(lsA + ao);
                if constexpr (SPLIT) afl[mt] = *(const half8*)(lsAl + ao);
            }
            #pragma unroll
            for (int nt = 0; nt < 4; ++nt) {
                int row = wn * 64 + nt * 16 + lr;
                int bo = row * 64 + (((kk * 4 + quad) ^ (row & 7)) << 3);
                half8 bf = *(const half8*)(lsB + bo);
                half8 bfl;
                if constexpr (SPLIT) bfl = *(const half8*)(lsBl + bo);
                #pragma unroll
                for (int mt = 0; mt < 4; ++mt) {
                    acc[mt][nt] = __builtin_amdgcn_mfma_f32_16x16x32_f16(af[mt], bf, acc[mt][nt], 0, 0, 0);
                    if constexpr (SPLIT) {
                        acc[mt][nt] = __builtin_amdgcn_mfma_f32_16x16x32_f16(af[mt], bfl, acc[mt][nt], 0, 0, 0);
                        acc[mt][nt] = __builtin_amdgcn_mfma_f32_16x16x32_f16(afl[mt], bf, acc[mt][nt], 0, 0, 0);
                    }
                }
            }
        }
        __syncthreads();
    }

    size_t zoff = ACC ? (size_t)blockIdx.z * M * N : 0;
    #pragma unroll
    for (int mt = 0; mt < 4; ++mt) {
        #pragma unroll
        for (int rr = 0; rr < 4; ++rr) {
            int row = row0 + wm * 64 + mt * 16 + quad * 4 + rr;
            if (row >= M) continue;
            #pragma unroll
            for (int nt = 0; nt < 4; ++nt) {
                int col = col0 + wn * 64 + nt * 16 + lr;
                float v = acc[mt][nt][rr];
                if (!ACC) {
                    v += bias[col];
                    if (do_relu) v = v > 0.f ? v : 0.f;
                }
                if (outmode) Ch[(size_t)row * N + col] = f2h(v);
                else         C[zoff + (size_t)row * N + col] = v;
            }
        }
    }
}

// finish for split-K head: out = relu(sum_z partials + bias), vectorized float4
__global__ __launch_bounds__(256) void head_fin(const float* __restrict__ part, const float* __restrict__ bo,
                                                float* __restrict__ out) {
    int i4 = blockIdx.x * 256 + threadIdx.x;
    const int TOT4 = NGRAPH * FPOUT / 4;
    if (i4 >= TOT4) return;
    int col4 = i4 & (FPOUT / 4 - 1);
    const size_t STRIDE4 = (size_t)NGRAPH * FPOUT / 4;
    const float4* p = (const float4*)part;
    float4 a = p[i4];
    float4 b = p[i4 + STRIDE4];
    float4 c = p[i4 + 2 * STRIDE4];
    float4 d = p[i4 + 3 * STRIDE4];
    float4 bb = ((const float4*)bo)[col4];
    float4 o;
    o.x = a.x + b.x + c.x + d.x + bb.x; o.x = o.x > 0.f ? o.x : 0.f;
    o.y = a.y + b.y + c.y + d.y + bb.y; o.y = o.y > 0.f ? o.y : 0.f;
    o.z = a.z + b.z + c.z + d.z + bb.z; o.z = o.z > 0.f ? o.z : 0.f;
    o.w = a.w + b.w + c.w + d.w + bb.w; o.w = o.w > 0.f ? o.w : 0.f;
    ((float4*)out)[i4] = o;
}

// ---------------- aggregation: row-major fp16 gather, 2 nodes/wave, 16-deep MLP ----------
// y[v] = sum_{s->v} xh[s]*w + xh[v]*dis[v]^2, fp32 accumulate, fp16 output.
// 16 edges per trip (s/w/g arrays of 16) -> 16 outstanding 1KB gathers per wave
// (R8 had 8); diagnosis: latency-bound (VALUBusy 33%, BW 46%, occ 34%).
// Per-node summation order unchanged -> bit-identical numerics to R8.
__global__ __launch_bounds__(256) void agg256b(const ushort* __restrict__ xh, ushort* __restrict__ yh,
                                               const float* __restrict__ dis,
                                               const int* __restrict__ offs, const int2* __restrict__ csr_pair) {
    constexpr int F = 256;
    int wave = threadIdx.x >> 6;
    int lane = threadIdx.x & 63;
    int half = lane >> 5;
    int sub  = lane & 31;                       // covers ushorts sub*8 .. sub*8+8
    int v = blockIdx.x * 8 + wave * 2 + half;   // 50000 % 8 == 0 -> always < NNODES
    int beg = offs[v], end = offs[v + 1];
    int len = end - beg;
    int leno = __shfl_xor(len, 32, 64);
    int maxlen = len > leno ? len : leno;       // uniform across wave

    float dv = dis[v];
    float sw = dv * dv;
    short8 a0 = ((const short8*)(xh + (size_t)v * F))[sub];
    float acc[8];
    #pragma unroll
    for (int j = 0; j < 8; ++j) acc[j] = h2f((ushort)a0[j]) * sw;

    for (int k = 0; k < maxlen; k += 16) {
        int   s[16];
        float w[16];
        #pragma unroll
        for (int u = 0; u < 16; ++u) {
            int idx = beg + k + u;
            bool val = idx < end;
            int ic = val ? idx : beg;
            int2 pr = csr_pair[ic];
            s[u] = pr.x;
            w[u] = val ? __int_as_float(pr.y) : 0.f;
        }
        short8 g[16];
        #pragma unroll
        for (int u = 0; u < 16; ++u)
            g[u] = ((const short8*)(xh + (size_t)s[u] * F))[sub];
        #pragma unroll
        for (int u = 0; u < 16; ++u) {
            #pragma unroll
            for (int j = 0; j < 8; ++j)
                acc[j] += h2f((ushort)g[u][j]) * w[u];
        }
    }

    ushort h[8];
    #pragma unroll
    for (int j = 0; j < 8; ++j) h[j] = f2h(acc[j]);
    short8 hv = {(short)h[0], (short)h[1], (short)h[2], (short)h[3], (short)h[4], (short)h[5], (short)h[6], (short)h[7]};
    ((short8*)(yh + (size_t)v * F))[sub] = hv;
}

// ---------------- fused gate+pool: per graph, 16 waves ----------------
__global__ __launch_bounds__(1024) void gatepool(const float* __restrict__ x, const float* __restrict__ pw,
                                                 const float* __restrict__ pb, const int* __restrict__ batch,
                                                 ushort* __restrict__ phi, ushort* __restrict__ plo, int n) {
    int g = blockIdx.x;
    int t = threadIdx.x;
    int wave = t >> 6, lane = t & 63;
    int lo_ = 0, hi_ = n;
    while (lo_ < hi_) { int mid = (lo_ + hi_) >> 1; if (batch[mid] < g) lo_ = mid + 1; else hi_ = mid; }
    int start = lo_;
    hi_ = n;
    while (lo_ < hi_) { int mid = (lo_ + hi_) >> 1; if (batch[mid] < g + 1) lo_ = mid + 1; else hi_ = mid; }
    int end = lo_;

    const float4* pwv = (const float4*)pw;
    float4 wa = pwv[lane], wb = pwv[lane + 64];
    float pb0 = pb[0];

    float4 s0 = make_float4(0.f, 0.f, 0.f, 0.f), s1 = s0;
    float4 m0 = make_float4(-INFINITY, -INFINITY, -INFINITY, -INFINITY), m1 = m0;

    for (int nn = start + wave; nn < end; nn += 16) {
        const float4* xr = (const float4*)(x + (size_t)nn * 512);
        float4 a = xr[lane];
        float4 b = xr[lane + 64];
        float p = a.x * wa.x + a.y * wa.y + a.z * wa.z + a.w * wa.w
                + b.x * wb.x + b.y * wb.y + b.z * wb.z + b.w * wb.w;
        #pragma unroll
        for (int off = 32; off; off >>= 1) p += __shfl_down(p, off, 64);
        float wg = __shfl(p, 0, 64);
        wg = 1.f / (1.f + expf(-(wg + pb0)));
        s0.x += a.x * wg; s0.y += a.y * wg; s0.z += a.z * wg; s0.w += a.w * wg;
        s1.x += b.x * wg; s1.y += b.y * wg; s1.z += b.z * wg; s1.w += b.w * wg;
        m0.x = fmaxf(m0.x, a.x); m0.y = fmaxf(m0.y, a.y); m0.z = fmaxf(m0.z, a.z); m0.w = fmaxf(m0.w, a.w);
        m1.x = fmaxf(m1.x, b.x); m1.y = fmaxf(m1.y, b.y); m1.z = fmaxf(m1.z, b.z); m1.w = fmaxf(m1.w, b.w);
    }

    __shared__ float ls[16][1024];
    *(float4*)&ls[wave][lane * 4]       = s0;
    *(float4*)&ls[wave][256 + lane * 4] = s1;
    *(float4*)&ls[wave][512 + lane * 4] = m0;
    *(float4*)&ls[wave][768 + lane * 4] = m1;
    __syncthreads();

    float val;
    if (t < 512) {
        float s = 0.f;
        #pragma unroll
        for (int wv = 0; wv < 16; ++wv) s += ls[wv][t];
        val = s;
    } else {
        float m = -INFINITY;
        #pragma unroll
        for (int wv = 0; wv < 16; ++wv) m = fmaxf(m, ls[wv][t]);
        if (start >= end) m = 0.f;
        val = m;
    }
    ushort h, l;
    split2h(val, h, l);
    size_t base = (size_t)g * 1024;
    phi[base + t] = h;
    plo[base + t] = l;
}

// ---------------- launch ----------------

extern "C" void kernel_launch(void* const* d_in, const int* in_sizes, int n_in,
                              void* d_out, int out_size, void* d_ws, size_t ws_size,
                              hipStream_t stream) {
    const float* x0    = (const float*)d_in[0];
    const int*   ei    = (const int*)d_in[1];
    const int*   batch = (const int*)d_in[2];
    const float* W1 = (const float*)d_in[3];
    const float* b1 = (const float*)d_in[4];
    const float* W2 = (const float*)d_in[5];
    const float* b2 = (const float*)d_in[6];
    const float* W3 = (const float*)d_in[7];
    const float* b3 = (const float*)d_in[8];
    const float* pw = (const float*)d_in[9];
    const float* pb = (const float*)d_in[10];
    const float* Wo = (const float*)d_in[11];
    const float* bo = (const float*)d_in[12];
    float* out = (float*)d_out;

    // workspace layout (float units, 16B-aligned regions)
    float* ws = (float*)d_ws;
    size_t off = 0;
    float* bufB = ws + off; off += (size_t)NNODES * 512;                 // x3 fp32 / head split-K partials
    ushort* xh  = (ushort*)(ws + off); off += (size_t)NNODES * 256 / 2;  // activation fp16 table (row-major)
    ushort* yh  = (ushort*)(ws + off); off += (size_t)NNODES * 256 / 2;  // agg out fp16 (row-major)
    int2*   tmp = (int2*)(ws + off);   off += (size_t)NNODES * 256 / 2;  // binA {s,d} intermediate
    ushort* W1thi = (ushort*)(ws + off); off += 256 * 256 / 2;
    ushort* W1tlo = (ushort*)(ws + off); off += 256 * 256 / 2;
    ushort* W2thi = (ushort*)(ws + off); off += 256 * 256 / 2;
    ushort* W2tlo = (ushort*)(ws + off); off += 256 * 256 / 2;
    ushort* W3thi = (ushort*)(ws + off); off += 512 * 256 / 2;
    ushort* W3tlo = (ushort*)(ws + off); off += 512 * 256 / 2;
    ushort* Wothi = (ushort*)(ws + off); off += (size_t)FPOUT * 1024 / 2;
    ushort* Wotlo = (ushort*)(ws + off); off += (size_t)FPOUT * 1024 / 2;
    ushort* phi = (ushort*)(ws + off); off += (size_t)NGRAPH * 1024 / 2;
    ushort* plo = (ushort*)(ws + off); off += (size_t)NGRAPH * 1024 / 2;
    float* dis  = ws + off; off += NNODES;
    int*   degi = (int*)(ws + off); off += NNODES;
    int*   offs = (int*)(ws + off); off += (NNODES + 4);
    int*   gcur = (int*)(ws + off); off += 256;                          // binA bucket cursors
    int2*  csr_pair = (int2*)(ws + off); off += 2 * (size_t)NEDGES;      // packed {src, w}
    int*   partials = (int*)(ws + off); off += 256;

    const int NB_N = (NNODES + 255) / 256;   // 196
    const int NB_E = (NEDGES + 255) / 256;
    const int NB_A = NNODES / 8;             // 6250 blocks, wave = 2 nodes
    const int MB128 = (NNODES + 127) / 128;  // 391

    // weight transpose+split (LDS-tiled, coalesced); layers use hi (= RNE fp16 W) only
    { dim3 g(256 / 32, 256 / 32);    wsplit_t<<<g, 256, 0, stream>>>(W1, W1thi, W1tlo, 256, 256); }
    { dim3 g(256 / 32, 256 / 32);    wsplit_t<<<g, 256, 0, stream>>>(W2, W2thi, W2tlo, 256, 256); }
    { dim3 g(512 / 32, 256 / 32);    wsplit_t<<<g, 256, 0, stream>>>(W3, W3thi, W3tlo, 256, 512); }
    { dim3 g(FPOUT / 32, 1024 / 32); wsplit_t<<<g, 256, 0, stream>>>(Wo, Wothi, Wotlo, 1024, FPOUT); }

    // CSR build: degree count -> offsets -> two-pass binning
    zero_i32<<<NB_N, 256, 0, stream>>>(degi, NNODES);
    count_deg<<<NB_E, 256, 0, stream>>>(ei, degi, NEDGES);
    calc_dis<<<NB_N, 256, 0, stream>>>(degi, dis, NNODES);
    scanA<<<NB_N, 256, 0, stream>>>(degi, offs, partials, NNODES);
    scanB<<<1, 256, 0, stream>>>(partials, NB_N);
    scanC<<<NB_N, 256, 0, stream>>>(offs, partials, NNODES);
    zero_i32<<<1, 256, 0, stream>>>(gcur, 256);
    binA<<<NEDGES / EPB, 256, 0, stream>>>(ei, offs, gcur, tmp, NEDGES);
    binB<<<NBUCK, 256, 0, stream>>>(tmp, offs, dis, csr_pair);

    // x0 -> fp16 table
    conv_f16<<<(NNODES * 256 / 4 + 255) / 256, 256, 0, stream>>>(x0, xh, NNODES * 256 / 4);

    // layer 1: y = A_norm @ x0h ; x1h = fp16(relu(y @ W1 + b1))
    agg256b<<<NB_A, 256, 0, stream>>>(xh, yh, dis, offs, csr_pair);
    {
        dim3 grid(H1 / 128, MB128);
        gemm_f16<0, 0, 256><<<grid, 256, 0, stream>>>(yh, nullptr, W1thi, nullptr, nullptr, xh, b1,
                                                      NNODES, H1, FIN, 1, 1);
    }
    // layer 2
    agg256b<<<NB_A, 256, 0, stream>>>(xh, yh, dis, offs, csr_pair);
    {
        dim3 grid(H2 / 128, MB128);
        gemm_f16<0, 0, 256><<<grid, 256, 0, stream>>>(yh, nullptr, W2thi, nullptr, nullptr, xh, b2,
                                                      NNODES, H2, H1, 1, 1);
    }
    // layer 3: agg on x2h, GEMM 256->512 -> fp32 (gatepool input)
    agg256b<<<NB_A, 256, 0, stream>>>(xh, yh, dis, offs, csr_pair);
    {
        dim3 grid(H3 / 128, MB128);
        gemm_f16<0, 0, 256><<<grid, 256, 0, stream>>>(yh, nullptr, W3thi, nullptr, bufB, nullptr, b3,
                                                      NNODES, H3, H2, 1, 0);
    }
    // fused gate+pool -> pooled fp16 hi/lo (Dekker pairs)
    gatepool<<<NGRAPH, 1024, 0, stream>>>(bufB, pw, pb, batch, phi, plo, NNODES);
    // head: split-K over 4 z-slices into bufB partials, then bias+relu finish.
    {
        dim3 grid(FPOUT / 128, (NGRAPH + 127) / 128, 4);
        gemm_f16<1, 1, 256><<<grid, 256, 0, stream>>>(phi, plo, Wothi, Wotlo, bufB, nullptr, nullptr,
                                                      NGRAPH, FPOUT, 1024, 0, 0);
    }
    head_fin<<<(NGRAPH * FPOUT / 4 + 255) / 256, 256, 0, stream>>>(bufB, bo, out);
}

// Round 11
// 507.562 us; speedup vs baseline: 1.6729x; 1.1834x over previous
//
#include <hip/hip_runtime.h>
#include <math.h>

#define NNODES 50000
#define NEDGES 800000
#define NGRAPH 512
#define FIN    256
#define H1     256
#define H2     256
#define H3     512
#define FPOUT  2048

#define NBUCK  196     // ceil(NNODES/256) coarse buckets (256 nodes each)
#define EPB    3200    // edges per binA block (250 blocks x 3200 = 800000 exactly)
#define BCAP   4864    // binB LDS chunk capacity
#define BKCAP  6144    // per-bucket capacity in padded tmp (mean 4096, sigma 64 -> +32 sigma)

typedef __attribute__((ext_vector_type(8))) short short8;
typedef __attribute__((ext_vector_type(8))) _Float16 half8;
typedef __attribute__((ext_vector_type(4))) float floatx4;
typedef __attribute__((ext_vector_type(4))) unsigned short ushx4;

// fp16 helpers: v_cvt_f16_f32 is RNE on gfx950
__device__ inline float h2f(ushort u) { return (float)__builtin_bit_cast(_Float16, u); }
__device__ inline ushort f2h(float x) { return __builtin_bit_cast(ushort, (_Float16)x); }
// Dekker split: a = hi + lo with hi = RNE-fp16(a); lo carries ~11 more mantissa bits.
__device__ inline void split2h(float a, ushort& h, ushort& l) {
    _Float16 hh = (_Float16)a;
    h = __builtin_bit_cast(ushort, hh);
    l = f2h(a - (float)hh);
}

// ---------------- utility kernels ----------------

__global__ __launch_bounds__(256) void zero_i32(int* p, int n) {
    int i = blockIdx.x * 256 + threadIdx.x;
    if (i < n) p[i] = 0;
}

__global__ __launch_bounds__(256) void calc_dis(const int* __restrict__ degi, float* __restrict__ dis, int n) {
    int i = blockIdx.x * 256 + threadIdx.x;
    if (i < n) dis[i] = rsqrtf((float)(degi[i] + 1));   // +1 self loop
}

__global__ __launch_bounds__(256) void scanA(const int* __restrict__ degi, int* __restrict__ offs,
                                             int* __restrict__ partials, int n) {
    __shared__ int sm[256];
    int t = threadIdx.x, idx = blockIdx.x * 256 + t;
    int v = (idx < n) ? degi[idx] : 0;
    sm[t] = v; __syncthreads();
    for (int d = 1; d < 256; d <<= 1) {
        int add = (t >= d) ? sm[t - d] : 0;
        __syncthreads();
        sm[t] += add;
        __syncthreads();
    }
    if (idx < n) offs[idx + 1] = sm[t];
    if (t == 255) partials[blockIdx.x] = sm[255];
}

__global__ __launch_bounds__(256) void scanB(int* __restrict__ partials, int nb) {
    __shared__ int sm[256];
    int t = threadIdx.x;
    int v = (t < nb) ? partials[t] : 0;
    sm[t] = v; __syncthreads();
    for (int d = 1; d < 256; d <<= 1) {
        int add = (t >= d) ? sm[t - d] : 0;
        __syncthreads();
        sm[t] += add;
        __syncthreads();
    }
    if (t < nb) partials[t] = sm[t] - v;   // exclusive
}

__global__ __launch_bounds__(256) void scanC(int* __restrict__ offs, const int* __restrict__ partials, int n) {
    int idx = blockIdx.x * 256 + threadIdx.x;
    if (idx < n) offs[idx + 1] += partials[blockIdx.x];
    if (idx == 0) offs[0] = 0;
}

// ---------------- CSR build: bucket binning, NO global random atomics ----------------
// binA: LDS counting-sort 3200 edges by coarse bucket (d>>8), reserve run space with one
// atomic per (block,bucket) (~49K total), write contiguous runs into PADDED tmp
// (bucket b at b*BKCAP). No offs dependency -> degree counting moves to binB1.
__global__ __launch_bounds__(256) void binA(const int* __restrict__ ei, int* __restrict__ gcur,
                                            int2* __restrict__ tmp, int e_total) {
    __shared__ int2 ls[EPB];
    __shared__ int2 ls2[EPB];
    __shared__ int hist[256], lpref[256], lcur[256], gbase[256];
    int tid = threadIdx.x;
    int e0 = blockIdx.x * EPB;
    int cnt = e_total - e0; if (cnt > EPB) cnt = EPB;
    hist[tid] = 0;
    __syncthreads();
    for (int i = tid; i < cnt; i += 256) {
        int s = ei[e0 + i];
        int d = ei[e_total + e0 + i];
        ls[i] = (int2){s, d};
        atomicAdd(&hist[d >> 8], 1);
    }
    __syncthreads();
    int hv = hist[tid];
    lpref[tid] = hv;
    __syncthreads();
    for (int dlt = 1; dlt < 256; dlt <<= 1) {
        int add = (tid >= dlt) ? lpref[tid - dlt] : 0;
        __syncthreads();
        lpref[tid] += add;
        __syncthreads();
    }
    int excl = lpref[tid] - hv;
    __syncthreads();
    lpref[tid] = excl;
    lcur[tid] = 0;
    __syncthreads();
    for (int i = tid; i < cnt; i += 256) {
        int2 pr = ls[i];
        int b = pr.y >> 8;
        int r = atomicAdd(&lcur[b], 1);
        ls2[lpref[b] + r] = pr;
    }
    if (tid < NBUCK) {
        int c = hist[tid];
        gbase[tid] = c ? atomicAdd(&gcur[tid], c) : 0;
    }
    __syncthreads();
    for (int i = tid; i < cnt; i += 256) {
        int2 pr = ls2[i];
        int b = pr.y >> 8;
        tmp[(size_t)b * BKCAP + gbase[b] + (i - lpref[b])] = pr;
    }
}

// binB1: per bucket, per-node degree via LDS atomics; coalesced degi write.
// Replaces count_deg's 800K device-scope random atomics (cross-XCD line ping-pong).
__global__ __launch_bounds__(256) void binB1(const int2* __restrict__ tmp, const int* __restrict__ gcur,
                                             int* __restrict__ degi) {
    __shared__ int cntN[256];
    int tid = threadIdx.x;
    int b = blockIdx.x;
    cntN[tid] = 0;
    __syncthreads();
    int tot = gcur[b];
    const int2* base = tmp + (size_t)b * BKCAP;
    for (int i = tid; i < tot; i += 256)
        atomicAdd(&cntN[base[i].y & 255], 1);
    __syncthreads();
    int node = (b << 8) + tid;
    if (node < NNODES) degi[node] = cntN[tid];
}

// binB2: per bucket, LDS-exact placement into csr_pair (writes land in an L2-held window).
__global__ __launch_bounds__(256) void binB2(const int2* __restrict__ tmp, const int* __restrict__ gcur,
                                             const int* __restrict__ offs, const float* __restrict__ dis,
                                             int2* __restrict__ csr_pair) {
    __shared__ int2 ls[BCAP];
    __shared__ int cntN[256];
    int tid = threadIdx.x;
    int b = blockIdx.x;
    int tot = gcur[b];
    const int2* base = tmp + (size_t)b * BKCAP;
    cntN[tid] = 0;
    __syncthreads();
    for (int c0 = 0; c0 < tot; c0 += BCAP) {
        int cc = tot - c0; if (cc > BCAP) cc = BCAP;
        for (int i = tid; i < cc; i += 256)
            ls[i] = base[c0 + i];
        __syncthreads();
        for (int i = tid; i < cc; i += 256) {
            int2 pr = ls[i];
            int d = pr.y;
            int r = atomicAdd(&cntN[d & 255], 1);
            float w = dis[pr.x] * dis[d];
            csr_pair[offs[d] + r] = (int2){pr.x, __float_as_int(w)};
        }
        __syncthreads();
    }
}

// W[K][N] fp32 -> Wt_hi[N][K], Wt_lo[N][K] (fp16 Dekker pair): LDS-tiled transpose
__global__ __launch_bounds__(256) void wsplit_t(const float* __restrict__ W, ushort* __restrict__ hi,
                                                ushort* __restrict__ lo, int K, int N) {
    __shared__ float sm[32][33];
    int tx = threadIdx.x & 31, ty = threadIdx.x >> 5;   // 32 x 8
    int n0 = blockIdx.x * 32, k0 = blockIdx.y * 32;
    #pragma unroll
    for (int j = 0; j < 32; j += 8)
        sm[ty + j][tx] = W[(size_t)(k0 + ty + j) * N + n0 + tx];
    __syncthreads();
    #pragma unroll
    for (int j = 0; j < 32; j += 8) {
        float a = sm[tx][ty + j];
        ushort h, l; split2h(a, h, l);
        size_t o = (size_t)(n0 + ty + j) * K + k0 + tx;
        hi[o] = h; lo[o] = l;
    }
}

// x fp32 -> fp16-RNE table (row-major [NNODES][256])
__global__ __launch_bounds__(256) void conv_f16(const float* __restrict__ x, ushort* __restrict__ xh, int total4) {
    int i = blockIdx.x * 256 + threadIdx.x;
    if (i >= total4) return;
    float4 a = ((const float4*)x)[i];
    ushx4 h = {f2h(a.x), f2h(a.y), f2h(a.z), f2h(a.w)};
    ((ushx4*)xh)[i] = h;
}

// ---------------- MFMA fp16 GEMM: BK=64, XOR-swizzled LDS, XCD-chunked blocks ----------------
// SPLIT=0: C = relu(A @ B^T + bias), single fp16 operands, 1 MFMA per frag pair.
// SPLIT=1: fp16 Dekker pairs, 3 MFMAs (~fp32-accurate). Head GEMM.
// ACC=1: raw acc to partial buffer C + z*M*N (split-K).
// outmode 1: write fp16 activation table row-major [M][N].
template<int SPLIT, int ACC, int KSPAN>
__global__ __launch_bounds__(256) void gemm_f16(const ushort* __restrict__ Ahp, const ushort* __restrict__ Alp,
                                                const ushort* __restrict__ Bhp, const ushort* __restrict__ Blp,
                                                float* __restrict__ C, ushort* __restrict__ Ch,
                                                const float* __restrict__ bias,
                                                int M, int N, int K, int do_relu, int outmode) {
    __shared__ _Float16 lsA[128 * 64];
    __shared__ _Float16 lsB[128 * 64];
    __shared__ _Float16 lsAl[SPLIT ? 128 * 64 : 8];
    __shared__ _Float16 lsBl[SPLIT ? 128 * 64 : 8];
    const _Float16* Ah = (const _Float16*)Ahp;
    const _Float16* Al = (const _Float16*)Alp;
    const _Float16* Bh = (const _Float16*)Bhp;
    const _Float16* Bl = (const _Float16*)Blp;

    int tid = threadIdx.x;
    int w = tid >> 6, lane = tid & 63;
    int quad = lane >> 4, lr = lane & 15;
    int wm = w & 1, wn = w >> 1;

    int gx = gridDim.x;
    int orig = blockIdx.y * gx + blockIdx.x;
    int nwg = gx * gridDim.y;
    int xcd = orig & 7, slot = orig >> 3;
    int q = nwg >> 3, r = nwg & 7;
    int wid = (xcd < r ? xcd * (q + 1) : r * (q + 1) + (xcd - r) * q) + slot;
    int row0 = (wid / gx) * 128, col0 = (wid % gx) * 128;
    int kb = blockIdx.z * KSPAN;

    floatx4 acc[4][4];
    #pragma unroll
    for (int i = 0; i < 4; ++i)
        #pragma unroll
        for (int j = 0; j < 4; ++j)
            acc[i][j] = (floatx4){0.f, 0.f, 0.f, 0.f};

    const half8 zer = {};
    int srow = tid >> 3;
    int sgran = tid & 7;
    int skk = sgran * 8;
    int sgx = (sgran ^ (srow & 7)) * 8;

    half8 pa[4], pb[4], pal[4], pbl[4];
    #pragma unroll
    for (int c = 0; c < 4; ++c) {
        int row = c * 32 + srow;
        bool mok = (row0 + row) < M;
        size_t aoff = (size_t)(row0 + row) * K + kb + skk;
        pa[c] = mok ? *(const half8*)(Ah + aoff) : zer;
        if constexpr (SPLIT) pal[c] = mok ? *(const half8*)(Al + aoff) : zer;
        size_t boff = (size_t)(col0 + row) * K + kb + skk;
        pb[c] = *(const half8*)(Bh + boff);
        if constexpr (SPLIT) pbl[c] = *(const half8*)(Bl + boff);
    }

    for (int k0 = kb; k0 < kb + KSPAN; k0 += 64) {
        #pragma unroll
        for (int c = 0; c < 4; ++c) {
            int lo = (c * 32 + srow) * 64 + sgx;
            *(half8*)(lsA + lo) = pa[c];
            *(half8*)(lsB + lo) = pb[c];
            if constexpr (SPLIT) { *(half8*)(lsAl + lo) = pal[c]; *(half8*)(lsBl + lo) = pbl[c]; }
        }
        __syncthreads();
        if (k0 + 64 < kb + KSPAN) {
            #pragma unroll
            for (int c = 0; c < 4; ++c) {
                int row = c * 32 + srow;
                bool mok = (row0 + row) < M;
                size_t aoff = (size_t)(row0 + row) * K + k0 + 64 + skk;
                pa[c] = mok ? *(const half8*)(Ah + aoff) : zer;
                if constexpr (SPLIT) pal[c] = mok ? *(const half8*)(Al + aoff) : zer;
                size_t boff = (size_t)(col0 + row) * K + k0 + 64 + skk;
                pb[c] = *(const half8*)(Bh + boff);
                if constexpr (SPLIT) pbl[c] = *(const half8*)(Bl + boff);
            }
        }
        #pragma unroll
        for (int kk = 0; kk < 2; ++kk) {
            half8 af[4], afl[4];
            #pragma unroll
            for (int mt = 0; mt < 4; ++mt) {
                int row = wm * 64 + mt * 16 + lr;
                int ao = row * 64 + (((kk * 4 + quad) ^ (row & 7)) << 3);
                af[mt] = *(const half8*)(lsA + ao);
                if constexpr (SPLIT) afl[mt] = *(const half8*)(lsAl + ao);
            }
            #pragma unroll
            for (int nt = 0; nt < 4; ++nt) {
                int row = wn * 64 + nt * 16 + lr;
                int bo = row * 64 + (((kk * 4 + quad) ^ (row & 7)) << 3);
                half8 bf = *(const half8*)(lsB + bo);
                half8 bfl;
                if constexpr (SPLIT) bfl = *(const half8*)(lsBl + bo);
                #pragma unroll
                for (int mt = 0; mt < 4; ++mt) {
                    acc[mt][nt] = __builtin_amdgcn_mfma_f32_16x16x32_f16(af[mt], bf, acc[mt][nt], 0, 0, 0);
                    if constexpr (SPLIT) {
                        acc[mt][nt] = __builtin_amdgcn_mfma_f32_16x16x32_f16(af[mt], bfl, acc[mt][nt], 0, 0, 0);
                        acc[mt][nt] = __builtin_amdgcn_mfma_f32_16x16x32_f16(afl[mt], bf, acc[mt][nt], 0, 0, 0);
                    }
                }
            }
        }
        __syncthreads();
    }

    size_t zoff = ACC ? (size_t)blockIdx.z * M * N : 0;
    #pragma unroll
    for (int mt = 0; mt < 4; ++mt) {
        #pragma unroll
        for (int rr = 0; rr < 4; ++rr) {
            int row = row0 + wm * 64 + mt * 16 + quad * 4 + rr;
            if (row >= M) continue;
            #pragma unroll
            for (int nt = 0; nt < 4; ++nt) {
                int col = col0 + wn * 64 + nt * 16 + lr;
                float v = acc[mt][nt][rr];
                if (!ACC) {
                    v += bias[col];
                    if (do_relu) v = v > 0.f ? v : 0.f;
                }
                if (outmode) Ch[(size_t)row * N + col] = f2h(v);
                else         C[zoff + (size_t)row * N + col] = v;
            }
        }
    }
}

// finish for split-K head: out = relu(sum_z partials + bias), vectorized float4
__global__ __launch_bounds__(256) void head_fin(const float* __restrict__ part, const float* __restrict__ bo,
                                                float* __restrict__ out) {
    int i4 = blockIdx.x * 256 + threadIdx.x;
    const int TOT4 = NGRAPH * FPOUT / 4;
    if (i4 >= TOT4) return;
    int col4 = i4 & (FPOUT / 4 - 1);
    const size_t STRIDE4 = (size_t)NGRAPH * FPOUT / 4;
    const float4* p = (const float4*)part;
    float4 a = p[i4];
    float4 b = p[i4 + STRIDE4];
    float4 c = p[i4 + 2 * STRIDE4];
    float4 d = p[i4 + 3 * STRIDE4];
    float4 bb = ((const float4*)bo)[col4];
    float4 o;
    o.x = a.x + b.x + c.x + d.x + bb.x; o.x = o.x > 0.f ? o.x : 0.f;
    o.y = a.y + b.y + c.y + d.y + bb.y; o.y = o.y > 0.f ? o.y : 0.f;
    o.z = a.z + b.z + c.z + d.z + bb.z; o.z = o.z > 0.f ? o.z : 0.f;
    o.w = a.w + b.w + c.w + d.w + bb.w; o.w = o.w > 0.f ? o.w : 0.f;
    ((float4*)out)[i4] = o;
}

// ---------------- aggregation: row-major fp16 gather, 2 nodes per wave (R8 form) ----------
// y[v] = sum_{s->v} xh[s]*w + xh[v]*dis[v]^2, fp32 accumulate, fp16 output.
// 8-wide gather batch is the compiler-friendly optimum (16-wide regressed: VGPR cap
// forced serialization, R10 80us vs 59us).
__global__ __launch_bounds__(256) void agg256b(const ushort* __restrict__ xh, ushort* __restrict__ yh,
                                               const float* __restrict__ dis,
                                               const int* __restrict__ offs, const int2* __restrict__ csr_pair) {
    constexpr int F = 256;
    int wave = threadIdx.x >> 6;
    int lane = threadIdx.x & 63;
    int half = lane >> 5;
    int sub  = lane & 31;                       // covers ushorts sub*8 .. sub*8+8
    int v = blockIdx.x * 8 + wave * 2 + half;   // 50000 % 8 == 0 -> always < NNODES
    int beg = offs[v], end = offs[v + 1];
    int len = end - beg;
    int leno = __shfl_xor(len, 32, 64);
    int maxlen = len > leno ? len : leno;       // uniform across wave

    float dv = dis[v];
    float sw = dv * dv;
    short8 a0 = ((const short8*)(xh + (size_t)v * F))[sub];
    float acc[8];
    #pragma unroll
    for (int j = 0; j < 8; ++j) acc[j] = h2f((ushort)a0[j]) * sw;

    for (int k = 0; k < maxlen; k += 8) {
        int   s[8];
        float w[8];
        #pragma unroll
        for (int u = 0; u < 8; ++u) {
            int idx = beg + k + u;
            bool val = idx < end;
            int ic = val ? idx : beg;
            int2 pr = csr_pair[ic];
            s[u] = pr.x;
            w[u] = val ? __int_as_float(pr.y) : 0.f;
        }
        short8 g[8];
        #pragma unroll
        for (int u = 0; u < 8; ++u)
            g[u] = ((const short8*)(xh + (size_t)s[u] * F))[sub];
        #pragma unroll
        for (int u = 0; u < 8; ++u) {
            #pragma unroll
            for (int j = 0; j < 8; ++j)
                acc[j] += h2f((ushort)g[u][j]) * w[u];
        }
    }

    ushort h[8];
    #pragma unroll
    for (int j = 0; j < 8; ++j) h[j] = f2h(acc[j]);
    short8 hv = {(short)h[0], (short)h[1], (short)h[2], (short)h[3], (short)h[4], (short)h[5], (short)h[6], (short)h[7]};
    ((short8*)(yh + (size_t)v * F))[sub] = hv;
}

// ---------------- fused gate+pool: per graph, 16 waves ----------------
__global__ __launch_bounds__(1024) void gatepool(const float* __restrict__ x, const float* __restrict__ pw,
                                                 const float* __restrict__ pb, const int* __restrict__ batch,
                                                 ushort* __restrict__ phi, ushort* __restrict__ plo, int n) {
    int g = blockIdx.x;
    int t = threadIdx.x;
    int wave = t >> 6, lane = t & 63;
    int lo_ = 0, hi_ = n;
    while (lo_ < hi_) { int mid = (lo_ + hi_) >> 1; if (batch[mid] < g) lo_ = mid + 1; else hi_ = mid; }
    int start = lo_;
    hi_ = n;
    while (lo_ < hi_) { int mid = (lo_ + hi_) >> 1; if (batch[mid] < g + 1) lo_ = mid + 1; else hi_ = mid; }
    int end = lo_;

    const float4* pwv = (const float4*)pw;
    float4 wa = pwv[lane], wb = pwv[lane + 64];
    float pb0 = pb[0];

    float4 s0 = make_float4(0.f, 0.f, 0.f, 0.f), s1 = s0;
    float4 m0 = make_float4(-INFINITY, -INFINITY, -INFINITY, -INFINITY), m1 = m0;

    for (int nn = start + wave; nn < end; nn += 16) {
        const float4* xr = (const float4*)(x + (size_t)nn * 512);
        float4 a = xr[lane];
        float4 b = xr[lane + 64];
        float p = a.x * wa.x + a.y * wa.y + a.z * wa.z + a.w * wa.w
                + b.x * wb.x + b.y * wb.y + b.z * wb.z + b.w * wb.w;
        #pragma unroll
        for (int off = 32; off; off >>= 1) p += __shfl_down(p, off, 64);
        float wg = __shfl(p, 0, 64);
        wg = 1.f / (1.f + expf(-(wg + pb0)));
        s0.x += a.x * wg; s0.y += a.y * wg; s0.z += a.z * wg; s0.w += a.w * wg;
        s1.x += b.x * wg; s1.y += b.y * wg; s1.z += b.z * wg; s1.w += b.w * wg;
        m0.x = fmaxf(m0.x, a.x); m0.y = fmaxf(m0.y, a.y); m0.z = fmaxf(m0.z, a.z); m0.w = fmaxf(m0.w, a.w);
        m1.x = fmaxf(m1.x, b.x); m1.y = fmaxf(m1.y, b.y); m1.z = fmaxf(m1.z, b.z); m1.w = fmaxf(m1.w, b.w);
    }

    __shared__ float ls[16][1024];
    *(float4*)&ls[wave][lane * 4]       = s0;
    *(float4*)&ls[wave][256 + lane * 4] = s1;
    *(float4*)&ls[wave][512 + lane * 4] = m0;
    *(float4*)&ls[wave][768 + lane * 4] = m1;
    __syncthreads();

    float val;
    if (t < 512) {
        float s = 0.f;
        #pragma unroll
        for (int wv = 0; wv < 16; ++wv) s += ls[wv][t];
        val = s;
    } else {
        float m = -INFINITY;
        #pragma unroll
        for (int wv = 0; wv < 16; ++wv) m = fmaxf(m, ls[wv][t]);
        if (start >= end) m = 0.f;
        val = m;
    }
    ushort h, l;
    split2h(val, h, l);
    size_t base = (size_t)g * 1024;
    phi[base + t] = h;
    plo[base + t] = l;
}

// ---------------- launch ----------------

extern "C" void kernel_launch(void* const* d_in, const int* in_sizes, int n_in,
                              void* d_out, int out_size, void* d_ws, size_t ws_size,
                              hipStream_t stream) {
    const float* x0    = (const float*)d_in[0];
    const int*   ei    = (const int*)d_in[1];
    const int*   batch = (const int*)d_in[2];
    const float* W1 = (const float*)d_in[3];
    const float* b1 = (const float*)d_in[4];
    const float* W2 = (const float*)d_in[5];
    const float* b2 = (const float*)d_in[6];
    const float* W3 = (const float*)d_in[7];
    const float* b3 = (const float*)d_in[8];
    const float* pw = (const float*)d_in[9];
    const float* pb = (const float*)d_in[10];
    const float* Wo = (const float*)d_in[11];
    const float* bo = (const float*)d_in[12];
    float* out = (float*)d_out;

    // workspace layout (float units, 16B-aligned regions)
    float* ws = (float*)d_ws;
    size_t off = 0;
    float* bufB = ws + off; off += (size_t)NNODES * 512;                 // x3 fp32 / head split-K partials
    ushort* xh  = (ushort*)(ws + off); off += (size_t)NNODES * 256 / 2;  // activation fp16 table (row-major)
    ushort* yh  = (ushort*)(ws + off); off += (size_t)NNODES * 256 / 2;  // agg out fp16 (row-major)
    int2*   tmp = (int2*)(ws + off);   off += (size_t)NNODES * 256 / 2;  // binA padded buckets (9.6MB of 25.6MB)
    ushort* W1thi = (ushort*)(ws + off); off += 256 * 256 / 2;
    ushort* W1tlo = (ushort*)(ws + off); off += 256 * 256 / 2;
    ushort* W2thi = (ushort*)(ws + off); off += 256 * 256 / 2;
    ushort* W2tlo = (ushort*)(ws + off); off += 256 * 256 / 2;
    ushort* W3thi = (ushort*)(ws + off); off += 512 * 256 / 2;
    ushort* W3tlo = (ushort*)(ws + off); off += 512 * 256 / 2;
    ushort* Wothi = (ushort*)(ws + off); off += (size_t)FPOUT * 1024 / 2;
    ushort* Wotlo = (ushort*)(ws + off); off += (size_t)FPOUT * 1024 / 2;
    ushort* phi = (ushort*)(ws + off); off += (size_t)NGRAPH * 1024 / 2;
    ushort* plo = (ushort*)(ws + off); off += (size_t)NGRAPH * 1024 / 2;
    float* dis  = ws + off; off += NNODES;
    int*   degi = (int*)(ws + off); off += NNODES;
    int*   offs = (int*)(ws + off); off += (NNODES + 4);
    int*   gcur = (int*)(ws + off); off += 256;                          // binA bucket cursors
    int2*  csr_pair = (int2*)(ws + off); off += 2 * (size_t)NEDGES;      // packed {src, w}
    int*   partials = (int*)(ws + off); off += 256;

    const int NB_N = (NNODES + 255) / 256;   // 196
    const int NB_A = NNODES / 8;             // 6250 blocks, wave = 2 nodes
    const int MB128 = (NNODES + 127) / 128;  // 391

    // weight transpose+split (LDS-tiled, coalesced); layers use hi (= RNE fp16 W) only
    { dim3 g(256 / 32, 256 / 32);    wsplit_t<<<g, 256, 0, stream>>>(W1, W1thi, W1tlo, 256, 256); }
    { dim3 g(256 / 32, 256 / 32);    wsplit_t<<<g, 256, 0, stream>>>(W2, W2thi, W2tlo, 256, 256); }
    { dim3 g(512 / 32, 256 / 32);    wsplit_t<<<g, 256, 0, stream>>>(W3, W3thi, W3tlo, 256, 512); }
    { dim3 g(FPOUT / 32, 1024 / 32); wsplit_t<<<g, 256, 0, stream>>>(Wo, Wothi, Wotlo, 1024, FPOUT); }

    // CSR build: bucket-sort edges (binA), per-node degrees from buckets (binB1, LDS-local),
    // offsets (scan), exact placement with weights (binB2). Zero random global atomics.
    zero_i32<<<1, 256, 0, stream>>>(gcur, 256);
    binA<<<NEDGES / EPB, 256, 0, stream>>>(ei, gcur, tmp, NEDGES);
    binB1<<<NBUCK, 256, 0, stream>>>(tmp, gcur, degi);
    calc_dis<<<NB_N, 256, 0, stream>>>(degi, dis, NNODES);
    scanA<<<NB_N, 256, 0, stream>>>(degi, offs, partials, NNODES);
    scanB<<<1, 256, 0, stream>>>(partials, NB_N);
    scanC<<<NB_N, 256, 0, stream>>>(offs, partials, NNODES);
    binB2<<<NBUCK, 256, 0, stream>>>(tmp, gcur, offs, dis, csr_pair);

    // x0 -> fp16 table
    conv_f16<<<(NNODES * 256 / 4 + 255) / 256, 256, 0, stream>>>(x0, xh, NNODES * 256 / 4);

    // layer 1: y = A_norm @ x0h ; x1h = fp16(relu(y @ W1 + b1))
    agg256b<<<NB_A, 256, 0, stream>>>(xh, yh, dis, offs, csr_pair);
    {
        dim3 grid(H1 / 128, MB128);
        gemm_f16<0, 0, 256><<<grid, 256, 0, stream>>>(yh, nullptr, W1thi, nullptr, nullptr, xh, b1,
                                                      NNODES, H1, FIN, 1, 1);
    }
    // layer 2
    agg256b<<<NB_A, 256, 0, stream>>>(xh, yh, dis, offs, csr_pair);
    {
        dim3 grid(H2 / 128, MB128);
        gemm_f16<0, 0, 256><<<grid, 256, 0, stream>>>(yh, nullptr, W2thi, nullptr, nullptr, xh, b2,
                                                      NNODES, H2, H1, 1, 1);
    }
    // layer 3: agg on x2h, GEMM 256->512 -> fp32 (gatepool input)
    agg256b<<<NB_A, 256, 0, stream>>>(xh, yh, dis, offs, csr_pair);
    {
        dim3 grid(H3 / 128, MB128);
        gemm_f16<0, 0, 256><<<grid, 256, 0, stream>>>(yh, nullptr, W3thi, nullptr, bufB, nullptr, b3,
                                                      NNODES, H3, H2, 1, 0);
    }
    // fused gate+pool -> pooled fp16 hi/lo (Dekker pairs)
    gatepool<<<NGRAPH, 1024, 0, stream>>>(bufB, pw, pb, batch, phi, plo, NNODES);
    // head: split-K over 4 z-slices into bufB partials, then bias+relu finish.
    {
        dim3 grid(FPOUT / 128, (NGRAPH + 127) / 128, 4);
        gemm_f16<1, 1, 256><<<grid, 256, 0, stream>>>(phi, plo, Wothi, Wotlo, bufB, nullptr, nullptr,
                                                      NGRAPH, FPOUT, 1024, 0, 0);
    }
    head_fin<<<(NGRAPH * FPOUT / 4 + 255) / 256, 256, 0, stream>>>(bufB, bo, out);
}